// Round 4
// baseline (1348.285 us; speedup 1.0000x reference)
//
#include <hip/hip_runtime.h>
#include <math.h>

#define C  2048
#define L  4096
#define L2 2048
#define CW3 6144  // C*3
#define NB 1024   // cooperative grid size (4 blocks/CU x 256 CUs)

// ---- small arrays in d_ws (float offsets) ----
constexpr size_t OFF_RS_A = 0;      // 2048
constexpr size_t OFF_RQ_A = 2048;   // 2048
constexpr size_t OFF_RS_B = 4096;   // 2048
constexpr size_t OFF_RQ_B = 6144;   // 2048
constexpr size_t OFF_SCAL = 8192;   // 16: [0]=meanA [1]=coefA [2]=meanB [3]=coefB [4]=sum(fc_b)
constexpr size_t OFF_CW   = 8208;   // 2048 colsum(fc_w)
constexpr size_t OFF_S    = 10256;  // 2048
constexpr size_t OFF_V    = 12304;  // 2048 (final, NO bias)
constexpr size_t OFF_O2   = 14352;  // 2048
constexpr size_t OFF_MIX  = 16400;  // 2048
constexpr size_t OFF_U    = 20496;  // 6144
constexpr size_t OFF_BAR  = 40960;  // 2 uints: [0]=arrive count (monotonic), [1]=generation

// ---- partials staged in d_out (fully overwritten by final stage) ----
constexpr size_t SC_CWP = 0;        // 32  x 2048
constexpr size_t SC_GP  = 65536;    // 64  x 6144
constexpr size_t SC_HP  = 458752;   // 64  x 6144
constexpr size_t SC_VP  = 851968;   // 128 x 2048
constexpr size_t SC_O2P = 1114112;  // 128 x 2048   (ends 1376256 < 8388608)

__device__ __forceinline__ float wredf(float v) {
#pragma unroll
  for (int o = 32; o; o >>= 1) v += __shfl_down(v, o, 64);
  return v;
}
__device__ __forceinline__ double wredd(double v) {
#pragma unroll
  for (int o = 32; o; o >>= 1) v += __shfl_down(v, o, 64);
  return v;
}
__device__ __forceinline__ float sigm(float x) { return 1.f / (1.f + expf(-x)); }
__device__ __forceinline__ float simam1(float x, float m, float cf) {
  float d = x - m;
  float y = d * d * cf + 0.5f;
  return x * (1.f + 1.f / (1.f + expf(-y)));
}

// ---- custom agent-scope grid barrier (monotonic count + generation flag) ----
__device__ __forceinline__ void gridbar(unsigned* cnt, unsigned* gen, unsigned g) {
  __syncthreads();
  if (threadIdx.x == 0) {
    __threadfence();  // release all prior writes at device scope
    unsigned prev = __hip_atomic_fetch_add(cnt, 1u, __ATOMIC_ACQ_REL,
                                           __HIP_MEMORY_SCOPE_AGENT);
    if (prev == g * NB - 1u) {
      __hip_atomic_store(gen, g, __ATOMIC_RELEASE, __HIP_MEMORY_SCOPE_AGENT);
    } else {
      while (__hip_atomic_load(gen, __ATOMIC_ACQUIRE, __HIP_MEMORY_SCOPE_AGENT) < g)
        __builtin_amdgcn_s_sleep(16);
    }
    __threadfence();  // acquire side
  }
  __syncthreads();
}

// ============================ stage bodies ============================

// S1 (4352 units): rowstats of input/insum + fc_w colsum partials (32)
__device__ void st1(int u, int tid, const float* __restrict__ A,
                    const float* __restrict__ B, const float* __restrict__ fc_w,
                    float* __restrict__ ws, float* __restrict__ sc) {
  if (u < 4096) {
    __shared__ float sm[8];
    const float* src = (u < 2048) ? A : B;
    int row = u & 2047;
    const float4* p = (const float4*)(src + (size_t)row * L);
    float s = 0.f, q = 0.f;
#pragma unroll
    for (int i = tid; i < L / 4; i += 256) {
      float4 v = p[i];
      s += (v.x + v.y) + (v.z + v.w);
      q += (v.x * v.x + v.y * v.y) + (v.z * v.z + v.w * v.w);
    }
    s = wredf(s); q = wredf(q);
    int lane = tid & 63, wv = tid >> 6;
    __syncthreads();
    if (!lane) { sm[wv] = s; sm[4 + wv] = q; }
    __syncthreads();
    if (!tid) {
      float* rs = ws + ((u < 2048) ? OFF_RS_A : OFF_RS_B);
      float* rq = ws + ((u < 2048) ? OFF_RQ_A : OFF_RQ_B);
      rs[row] = sm[0] + sm[1] + sm[2] + sm[3];
      rq[row] = sm[4] + sm[5] + sm[6] + sm[7];
    }
  } else {
    int cb = u - 4096;                    // 0..255
    int col = (cb & 7) * 256 + tid;
    int rg = cb >> 3;                     // 0..31 (64 rows each)
    const float* p = fc_w + (size_t)rg * 64 * C + col;
    float acc = 0.f;
#pragma unroll 8
    for (int k = 0; k < 64; ++k) acc += p[(size_t)k * C];
    (sc + SC_CWP)[rg * C + col] = acc;
  }
}

// S2 (2057 units): s (2048) + cw final (8) + scalars (1)
__device__ void st2(int u, int tid, const float* __restrict__ fc_w,
                    const float* __restrict__ fc_b, float* __restrict__ ws,
                    const float* __restrict__ sc) {
  if (u < 2048) {
    __shared__ float sl[4];
    const float4* w = (const float4*)(fc_w + (size_t)u * C);
    const float4* rx = (const float4*)(ws + OFF_RS_A);
    float acc = 0.f;
#pragma unroll
    for (int i = tid; i < C / 4; i += 256) {
      float4 a = w[i], r = rx[i];
      acc += a.x * r.x + a.y * r.y + a.z * r.z + a.w * r.w;
    }
    acc = wredf(acc);
    int lane = tid & 63, wv = tid >> 6;
    __syncthreads();
    if (!lane) sl[wv] = acc;
    __syncthreads();
    if (!tid)
      (ws + OFF_S)[u] = 0.5f * (sl[0] + sl[1] + sl[2] + sl[3]) + (float)L2 * fc_b[u];
  } else if (u < 2056) {
    int i = (u - 2048) * 256 + tid;
    float acc = 0.f;
#pragma unroll
    for (int r = 0; r < 32; ++r) acc += (sc + SC_CWP)[r * C + i];
    (ws + OFF_CW)[i] = acc;
  } else {
    __shared__ double sd[5];
    int lane = tid & 63, wv = tid >> 6;
    const float* arr = ws + (wv == 0 ? OFF_RS_A : wv == 1 ? OFF_RQ_A
                                                          : wv == 2 ? OFF_RS_B : OFF_RQ_B);
    double acc = 0.0, accb = 0.0;
    for (int i = lane; i < 2048; i += 64) {
      acc += (double)arr[i];
      if (wv == 0) accb += (double)fc_b[i];
    }
    acc = wredd(acc);
    if (wv == 0) accb = wredd(accb);
    __syncthreads();
    if (!lane) { sd[wv] = acc; if (wv == 0) sd[4] = accb; }
    __syncthreads();
    if (!tid) {
      const double N = (double)C * (double)L, n = N - 1.0;
      double dA = sd[1] - sd[0] * sd[0] / N;
      double dB = sd[3] - sd[2] * sd[2] / N;
      float* s = ws + OFF_SCAL;
      s[0] = (float)(sd[0] / N);
      s[1] = (float)(1.0 / (4.0 * (dA / n + 1e-4)));
      s[2] = (float)(sd[2] / N);
      s[3] = (float)(1.0 / (4.0 * (dB / n + 1e-4)));
      s[4] = (float)sd[4];
    }
  }
}

// S3 (1536 units): g/h partials (64 rowgroups of 32) — no atomics
__device__ void st3(int u, int tid, const float* __restrict__ conv1_w,
                    const float* __restrict__ ws, float* __restrict__ sc) {
  __shared__ float shl[32], shs[32];
  int col = (u % 24) * 256 + tid;  // [0, 6144)
  int rg = u / 24;                 // 0..63
  int i0 = rg * 32;
  __syncthreads();
  if (tid < 32) {
    shl[tid] = (ws + OFF_CW)[i0 + tid];
    shs[tid] = (ws + OFF_S)[i0 + tid];
  }
  __syncthreads();
  const float* base = conv1_w + (size_t)i0 * CW3 + col;
  float ag = 0.f, ah = 0.f;
#pragma unroll 8
  for (int k = 0; k < 32; ++k) {
    float wv = base[(size_t)k * CW3];
    ag += shl[k] * wv;
    ah += shs[k] * wv;
  }
  (sc + SC_GP)[(size_t)rg * CW3 + col] = ag;
  (sc + SC_HP)[(size_t)rg * CW3 + col] = ah;
}

// S4 (1024 units): reduce g/h window + V/O2 partials (128 c-tiles of 16 ch)
__device__ void st4(int u, int tid, const float* __restrict__ insum,
                    float* __restrict__ sc) {
  __shared__ float gsh[48], hsh[48];
  int kb = u & 7, cb = u >> 3;     // cb 0..127
  int c0 = cb * 16;
  int k = kb * 256 + tid;
  __syncthreads();
  if (tid < 48) {
    float a = 0.f;
#pragma unroll 8
    for (int p = 0; p < 64; ++p) a += (sc + SC_GP)[(size_t)p * CW3 + c0 * 3 + tid];
    gsh[tid] = a;
  } else if (tid >= 64 && tid < 112) {
    int t = tid - 64;
    float a = 0.f;
#pragma unroll 8
    for (int p = 0; p < 64; ++p) a += (sc + SC_HP)[(size_t)p * CW3 + c0 * 3 + t];
    hsh[t] = a;
  }
  __syncthreads();
  float accv = 0.f, acco = 0.f;
#pragma unroll
  for (int c = 0; c < 16; ++c) {
    const float* row = insum + (size_t)(c0 + c) * L;
    float2 bm = *(const float2*)(row + 2 * k);
    float xc = (bm.x + bm.y) * 0.5f;
    float xl = 0.f, xr = 0.f;
    if (k > 0) {
      float2 am = *(const float2*)(row + 2 * k - 2);
      xl = (am.x + am.y) * 0.5f;
    }
    if (k < L2 - 1) {
      float2 dm = *(const float2*)(row + 2 * k + 2);
      xr = (dm.x + dm.y) * 0.5f;
    }
    accv += gsh[c * 3] * xl + gsh[c * 3 + 1] * xc + gsh[c * 3 + 2] * xr;
    acco += hsh[c * 3] * xl + hsh[c * 3 + 1] * xc + hsh[c * 3 + 2] * xr;
  }
  (sc + SC_VP)[(size_t)cb * L2 + k] = accv;
  (sc + SC_O2P)[(size_t)cb * L2 + k] = acco;
}

// S4b (64 units): reduce 128 partials -> final V / O2 (direct store, no atomics)
__device__ void st4b(int u, int tid, const float* __restrict__ sc,
                     float* __restrict__ ws) {
  __shared__ float red[256];
  int arr = u & 1, seg = u >> 1;            // seg 0..31
  int kk = seg * 64 + (tid & 63);
  int pq = tid >> 6;                        // 0..3
  const float* base = sc + (arr ? SC_O2P : SC_VP);
  float s = 0.f;
#pragma unroll 8
  for (int p = pq * 32; p < pq * 32 + 32; ++p) s += base[(size_t)p * L2 + kk];
  __syncthreads();
  red[tid] = s;
  __syncthreads();
  if (tid < 64) {
    float tot = red[tid] + red[tid + 64] + red[tid + 128] + red[tid + 192];
    ws[(arr ? OFF_O2 : OFF_V) + seg * 64 + tid] = tot;
  }
}

// S5 (2048 units): U correlations; v staged in LDS with bias folded
__device__ void st5(int u, int tid, const float* __restrict__ input,
                    float* __restrict__ ws) {
  __shared__ float vsh[2050];
  __shared__ float s12[12];
  float sb = (ws + OFF_SCAL)[4];
  __syncthreads();
  if (tid == 0) { vsh[0] = 0.f; vsh[2049] = 0.f; }
  for (int j = tid; j < L2; j += 256) vsh[1 + j] = (ws + OFF_V)[j] + sb;
  __syncthreads();
  float a0 = 0.f, a1 = 0.f, a2 = 0.f;
#pragma unroll
  for (int j = tid; j < L2; j += 256) {
    float2 ab = *(const float2*)(input + (size_t)u * L + 2 * j);
    float xm = (ab.x + ab.y) * 0.5f;
    a0 += xm * vsh[j + 2];
    a1 += xm * vsh[j + 1];
    a2 += xm * vsh[j];
  }
  a0 = wredf(a0); a1 = wredf(a1); a2 = wredf(a2);
  int lane = tid & 63, wv = tid >> 6;
  __syncthreads();
  if (!lane) { s12[wv] = a0; s12[4 + wv] = a1; s12[8 + wv] = a2; }
  __syncthreads();
  if (!tid) {
    (ws + OFF_U)[u * 3 + 0] = s12[0] + s12[1] + s12[2] + s12[3];
    (ws + OFF_U)[u * 3 + 1] = s12[4] + s12[5] + s12[6] + s12[7];
    (ws + OFF_U)[u * 3 + 2] = s12[8] + s12[9] + s12[10] + s12[11];
  }
}

// S6 (2048 units): out1 dot + mix
__device__ void st6(int u, int tid, const float* __restrict__ conv1_w,
                    const float* __restrict__ mix_w, float* __restrict__ ws) {
  __shared__ float sl[4];
  const float4* w4 = (const float4*)(conv1_w + (size_t)u * CW3);
  const float4* u4 = (const float4*)(ws + OFF_U);
  float acc = 0.f;
#pragma unroll
  for (int m = tid; m < CW3 / 4; m += 256) {
    float4 wv = w4[m], uv = u4[m];
    acc += wv.x * uv.x + wv.y * uv.y + wv.z * uv.z + wv.w * uv.w;
  }
  acc = wredf(acc);
  int lane = tid & 63, wv = tid >> 6;
  __syncthreads();
  if (!lane) sl[wv] = acc;
  __syncthreads();
  if (!tid) {
    float mfv = sigm(mix_w[0]);
    float o1 = sigm(sl[0] + sl[1] + sl[2] + sl[3]);
    float o2 = sigm((ws + OFF_O2)[u]);
    (ws + OFF_MIX)[u] = o1 * mfv + o2 * (1.f - mfv);
  }
}

// S8 (2048 units): per-row ov (mid-tap dot) + final elementwise
__device__ void st8(int u, int tid, const float* __restrict__ input,
                    const float* __restrict__ insum,
                    const float* __restrict__ conv1_w,
                    float* __restrict__ out, const float* __restrict__ ws) {
  __shared__ float sl[4];
  __shared__ float shov;
  const float4* w4 = (const float4*)(conv1_w + (size_t)u * CW3);
  const float4* m4 = (const float4*)(ws + OFF_MIX);
  float acc = 0.f;
#pragma unroll
  for (int p = tid; p < 512; p += 256) {
    float4 f0 = w4[3 * p], f1 = w4[3 * p + 1], f2 = w4[3 * p + 2];
    float4 m = m4[p];
    acc += f0.y * m.x + f1.x * m.y + f1.w * m.z + f2.z * m.w;
  }
  acc = wredf(acc);
  int lane = tid & 63, wv = tid >> 6;
  __syncthreads();
  if (!lane) sl[wv] = acc;
  __syncthreads();
  if (!tid) shov = sigm(sl[0] + sl[1] + sl[2] + sl[3]);
  __syncthreads();
  float ovc = shov;
  const float* scal = ws + OFF_SCAL;
  float mA = scal[0], cA = scal[1], mB = scal[2], cB = scal[3];
  size_t base = (size_t)u * L;
  const float4* pa = (const float4*)(input + base);
  const float4* pb = (const float4*)(insum + base);
  float4* po = (float4*)(out + base);
#pragma unroll
  for (int i = tid; i < L / 4; i += 256) {
    float4 a = pa[i], b = pb[i], r;
    r.x = (simam1(a.x, mA, cA) * 0.6f + simam1(b.x, mB, cB) * 0.4f) * ovc;
    r.y = (simam1(a.y, mA, cA) * 0.6f + simam1(b.y, mB, cB) * 0.4f) * ovc;
    r.z = (simam1(a.z, mA, cA) * 0.6f + simam1(b.z, mB, cB) * 0.4f) * ovc;
    r.w = (simam1(a.w, mA, cA) * 0.6f + simam1(b.w, mB, cB) * 0.4f) * ovc;
    po[i] = r;
  }
}

// ====================== cooperative mega-kernel ======================
__global__ __launch_bounds__(256, 4) void mega(
    const float* __restrict__ input, const float* __restrict__ insum,
    const float* __restrict__ conv1_w, const float* __restrict__ fc_w,
    const float* __restrict__ fc_b, const float* __restrict__ mix_w,
    float* __restrict__ out, float* __restrict__ ws) {
  float* sc = out;
  unsigned* cnt = (unsigned*)(ws + OFF_BAR);
  unsigned* gen = cnt + 1;
  const int tid = threadIdx.x;

  for (int u = blockIdx.x; u < 4352; u += NB) st1(u, tid, input, insum, fc_w, ws, sc);
  gridbar(cnt, gen, 1);
  for (int u = blockIdx.x; u < 2057; u += NB) st2(u, tid, fc_w, fc_b, ws, sc);
  gridbar(cnt, gen, 2);
  for (int u = blockIdx.x; u < 1536; u += NB) st3(u, tid, conv1_w, ws, sc);
  gridbar(cnt, gen, 3);
  for (int u = blockIdx.x; u < 1024; u += NB) st4(u, tid, insum, sc);
  gridbar(cnt, gen, 4);
  for (int u = blockIdx.x; u < 64; u += NB) st4b(u, tid, sc, ws);
  gridbar(cnt, gen, 5);
  for (int u = blockIdx.x; u < 2048; u += NB) st5(u, tid, input, ws);
  gridbar(cnt, gen, 6);
  for (int u = blockIdx.x; u < 2048; u += NB) st6(u, tid, conv1_w, mix_w, ws);
  gridbar(cnt, gen, 7);
  for (int u = blockIdx.x; u < 2048; u += NB) st8(u, tid, input, insum, conv1_w, out, ws);
}

// ================= fallback: thin per-stage wrappers =================
__global__ void wS1(const float* A, const float* B, const float* fc_w, float* ws,
                    float* sc) { st1(blockIdx.x, threadIdx.x, A, B, fc_w, ws, sc); }
__global__ void wS2(const float* fc_w, const float* fc_b, float* ws, const float* sc) {
  st2(blockIdx.x, threadIdx.x, fc_w, fc_b, ws, sc);
}
__global__ void wS3(const float* conv1_w, const float* ws, float* sc) {
  st3(blockIdx.x, threadIdx.x, conv1_w, ws, sc);
}
__global__ void wS4(const float* insum, float* sc) { st4(blockIdx.x, threadIdx.x, insum, sc); }
__global__ void wS4b(const float* sc, float* ws) { st4b(blockIdx.x, threadIdx.x, sc, ws); }
__global__ void wS5(const float* input, float* ws) { st5(blockIdx.x, threadIdx.x, input, ws); }
__global__ void wS6(const float* conv1_w, const float* mix_w, float* ws) {
  st6(blockIdx.x, threadIdx.x, conv1_w, mix_w, ws);
}
__global__ void wS8(const float* input, const float* insum, const float* conv1_w,
                    float* out, const float* ws) {
  st8(blockIdx.x, threadIdx.x, input, insum, conv1_w, out, ws);
}

extern "C" void kernel_launch(void* const* d_in, const int* in_sizes, int n_in,
                              void* d_out, int out_size, void* d_ws, size_t ws_size,
                              hipStream_t stream) {
  const float* input   = (const float*)d_in[0];
  const float* insum   = (const float*)d_in[1];
  const float* conv1_w = (const float*)d_in[2];
  const float* fc_w    = (const float*)d_in[3];
  const float* fc_b    = (const float*)d_in[4];
  const float* mix_w   = (const float*)d_in[5];
  float* out = (float*)d_out;
  float* ws  = (float*)d_ws;
  float* sc  = out;

  // zero the barrier words (captured as a memset node)
  hipMemsetAsync((char*)d_ws + OFF_BAR * 4, 0, 8, stream);

  void* args[] = {(void*)&input, (void*)&insum, (void*)&conv1_w, (void*)&fc_w,
                  (void*)&fc_b, (void*)&mix_w, (void*)&out, (void*)&ws};
  hipError_t err = hipLaunchCooperativeKernel((const void*)mega, dim3(NB), dim3(256),
                                              args, 0, stream);
  if (err != hipSuccess) {
    dim3 b(256);
    wS1<<<4352, b, 0, stream>>>(input, insum, fc_w, ws, sc);
    wS2<<<2057, b, 0, stream>>>(fc_w, fc_b, ws, sc);
    wS3<<<1536, b, 0, stream>>>(conv1_w, ws, sc);
    wS4<<<1024, b, 0, stream>>>(insum, sc);
    wS4b<<<64, b, 0, stream>>>(sc, ws);
    wS5<<<2048, b, 0, stream>>>(input, ws);
    wS6<<<2048, b, 0, stream>>>(conv1_w, mix_w, ws);
    wS8<<<2048, b, 0, stream>>>(input, insum, conv1_w, out, ws);
  }
}

// Round 5
// 235.556 us; speedup vs baseline: 5.7238x; 5.7238x over previous
//
#include <hip/hip_runtime.h>
#include <math.h>

#define C  2048
#define L  4096
#define L2 2048
#define CW3 6144  // C*3

// ---- d_ws layout (float offsets) ----
constexpr size_t OFF_RS_A = 0;      // 2048
constexpr size_t OFF_RQ_A = 2048;   // 2048
constexpr size_t OFF_RS_B = 4096;   // 2048
constexpr size_t OFF_RQ_B = 6144;   // 2048
constexpr size_t OFF_SCAL = 8192;   // 16: [0]=meanA [1]=coefA [2]=meanB [3]=coefB [4]=sum(fc_b)
// ---- atomic region (zeroed by captured memset): floats 8208..26639 ----
constexpr size_t OFF_CW   = 8208;   // 2048  colsum(fc_w)
constexpr size_t OFF_G    = 10256;  // 6144
constexpr size_t OFF_H    = 16400;  // 6144
constexpr size_t OFF_V    = 22544;  // 2048  (no bias)
constexpr size_t OFF_O2   = 24592;  // 2048
// ---- plain ----
constexpr size_t OFF_S    = 26640;  // 2048
constexpr size_t OFF_U    = 28688;  // 6144
constexpr size_t OFF_MIX  = 34832;  // 2048
// total 36880 floats = 147.5 KB (proven ws_size >= 164 KB)

// pooled tensors staged in d_out (exactly fills it; overwritten by w7)
constexpr size_t PA_OFF = 0;         // pooled input  2048x2048
constexpr size_t PB_OFF = 4194304;   // pooled insum  2048x2048

__device__ __forceinline__ float wredf(float v) {
#pragma unroll
  for (int o = 32; o; o >>= 1) v += __shfl_down(v, o, 64);
  return v;
}
__device__ __forceinline__ double wredd(double v) {
#pragma unroll
  for (int o = 32; o; o >>= 1) v += __shfl_down(v, o, 64);
  return v;
}
__device__ __forceinline__ float sigm(float x) { return 1.f / (1.f + expf(-x)); }
__device__ __forceinline__ float simam1(float x, float m, float cf) {
  float d = x - m;
  float y = d * d * cf + 0.5f;
  return x * (1.f + 1.f / (1.f + expf(-y)));
}

// ===== w1: rowstats + pooled write (4096) | cw atomics (256) =====
__global__ void w1(const float* __restrict__ A, const float* __restrict__ B,
                   const float* __restrict__ fc_w, float* __restrict__ ws,
                   float* __restrict__ dout) {
  int u = blockIdx.x;
  int tid = threadIdx.x;
  if (u < 4096) {
    __shared__ float sm[8];
    const float* src = (u < 2048) ? A : B;
    int row = u & 2047;
    const float4* p = (const float4*)(src + (size_t)row * L);
    float2* pool = (float2*)(dout + ((u < 2048) ? PA_OFF : PB_OFF) + (size_t)row * L2);
    float s = 0.f, q = 0.f;
#pragma unroll
    for (int i = tid; i < L / 4; i += 256) {
      float4 v = p[i];
      s += (v.x + v.y) + (v.z + v.w);
      q += (v.x * v.x + v.y * v.y) + (v.z * v.z + v.w * v.w);
      float2 pm;
      pm.x = (v.x + v.y) * 0.5f;
      pm.y = (v.z + v.w) * 0.5f;
      pool[i] = pm;
    }
    s = wredf(s); q = wredf(q);
    int lane = tid & 63, wv = tid >> 6;
    if (!lane) { sm[wv] = s; sm[4 + wv] = q; }
    __syncthreads();
    if (!tid) {
      float* rs = ws + ((u < 2048) ? OFF_RS_A : OFF_RS_B);
      float* rq = ws + ((u < 2048) ? OFF_RQ_A : OFF_RQ_B);
      rs[row] = sm[0] + sm[1] + sm[2] + sm[3];
      rq[row] = sm[4] + sm[5] + sm[6] + sm[7];
    }
  } else {
    int cb = u - 4096;            // 0..255
    int rg = cb >> 3;             // 0..31, 64 rows each
    int col = (cb & 7) * 256 + tid;
    const float* p = fc_w + (size_t)rg * 64 * C + col;
    float acc = 0.f;
#pragma unroll 8
    for (int k = 0; k < 64; ++k) acc += p[(size_t)k * C];
    atomicAdd(ws + OFF_CW + col, acc);
  }
}

// ===== w2: s (2048) + scalars (1) =====
__global__ void w2(const float* __restrict__ fc_w, const float* __restrict__ fc_b,
                   float* __restrict__ ws) {
  int u = blockIdx.x;
  int tid = threadIdx.x;
  int lane = tid & 63, wv = tid >> 6;
  if (u < 2048) {
    __shared__ float sl[4];
    const float4* w = (const float4*)(fc_w + (size_t)u * C);
    const float4* rx = (const float4*)(ws + OFF_RS_A);
    float acc = 0.f;
#pragma unroll
    for (int i = tid; i < C / 4; i += 256) {
      float4 a = w[i], r = rx[i];
      acc += a.x * r.x + a.y * r.y + a.z * r.z + a.w * r.w;
    }
    acc = wredf(acc);
    if (!lane) sl[wv] = acc;
    __syncthreads();
    if (!tid)
      (ws + OFF_S)[u] = 0.5f * (sl[0] + sl[1] + sl[2] + sl[3]) + (float)L2 * fc_b[u];
  } else {
    __shared__ double sd[5];
    const float* arr = ws + (wv == 0 ? OFF_RS_A : wv == 1 ? OFF_RQ_A
                                                          : wv == 2 ? OFF_RS_B : OFF_RQ_B);
    double acc = 0.0, accb = 0.0;
    for (int i = lane; i < 2048; i += 64) {
      acc += (double)arr[i];
      if (wv == 0) accb += (double)fc_b[i];
    }
    acc = wredd(acc);
    if (wv == 0) accb = wredd(accb);
    if (!lane) { sd[wv] = acc; if (wv == 0) sd[4] = accb; }
    __syncthreads();
    if (!tid) {
      const double N = (double)C * (double)L, n = N - 1.0;
      double dA = sd[1] - sd[0] * sd[0] / N;
      double dB = sd[3] - sd[2] * sd[2] / N;
      float* s = ws + OFF_SCAL;
      s[0] = (float)(sd[0] / N);
      s[1] = (float)(1.0 / (4.0 * (dA / n + 1e-4)));
      s[2] = (float)(sd[2] / N);
      s[3] = (float)(1.0 / (4.0 * (dB / n + 1e-4)));
      s[4] = (float)sd[4];
    }
  }
}

// ===== w3: g,h via atomics; grid 24 colchunks x 32 rowgroups = 768 =====
__global__ void w3(const float* __restrict__ conv1_w, float* __restrict__ ws) {
  __shared__ float lcw[64], ls[64];
  int u = blockIdx.x;
  int tid = threadIdx.x;
  int cc = u % 24, rg = u / 24;
  int col = cc * 256 + tid;
  int i0 = rg * 64;
  if (tid < 64) {
    lcw[tid] = (ws + OFF_CW)[i0 + tid];
    ls[tid] = (ws + OFF_S)[i0 + tid];
  }
  __syncthreads();
  const float* base = conv1_w + (size_t)i0 * CW3 + col;
  float ag = 0.f, ah = 0.f;
#pragma unroll 8
  for (int k = 0; k < 64; ++k) {
    float wv = base[(size_t)k * CW3];
    ag += lcw[k] * wv;
    ah += ls[k] * wv;
  }
  atomicAdd(ws + OFF_G + col, ag);
  atomicAdd(ws + OFF_H + col, ah);
}

// ===== w4: v,o2 via atomics from pooled insum; grid 8 k x 128 cgroups =====
__global__ void w4(const float* __restrict__ dout, float* __restrict__ ws) {
  __shared__ float gsh[48], hsh[48];
  int u = blockIdx.x;
  int tid = threadIdx.x;
  int kb = u & 7, cg = u >> 3;  // cg 0..127
  int c0 = cg * 16;
  int k = kb * 256 + tid;
  if (tid < 48) gsh[tid] = (ws + OFF_G)[c0 * 3 + tid];
  else if (tid >= 64 && tid < 112) hsh[tid - 64] = (ws + OFF_H)[c0 * 3 + tid - 64];
  __syncthreads();
  float accv = 0.f, acco = 0.f;
#pragma unroll
  for (int c = 0; c < 16; ++c) {
    const float* row = dout + PB_OFF + (size_t)(c0 + c) * L2;
    float xc = row[k];
    float xl = (k > 0) ? row[k - 1] : 0.f;
    float xr = (k < L2 - 1) ? row[k + 1] : 0.f;
    accv += gsh[c * 3] * xl + gsh[c * 3 + 1] * xc + gsh[c * 3 + 2] * xr;
    acco += hsh[c * 3] * xl + hsh[c * 3 + 1] * xc + hsh[c * 3 + 2] * xr;
  }
  atomicAdd(ws + OFF_V + k, accv);
  atomicAdd(ws + OFF_O2 + k, acco);
}

// ===== w5: U correlations from pooled input; v (bias folded) in LDS =====
__global__ void w5(const float* __restrict__ dout, float* __restrict__ ws) {
  __shared__ float vsh[2050];
  __shared__ float s12[12];
  int u = blockIdx.x;
  int tid = threadIdx.x;
  float sb = (ws + OFF_SCAL)[4];
  if (tid == 0) { vsh[0] = 0.f; vsh[2049] = 0.f; }
  for (int j = tid; j < L2; j += 256) vsh[1 + j] = (ws + OFF_V)[j] + sb;
  __syncthreads();
  const float* prow = dout + PA_OFF + (size_t)u * L2;
  float a0 = 0.f, a1 = 0.f, a2 = 0.f;
#pragma unroll
  for (int j = tid; j < L2; j += 256) {
    float xm = prow[j];
    a0 += xm * vsh[j + 2];
    a1 += xm * vsh[j + 1];
    a2 += xm * vsh[j];
  }
  a0 = wredf(a0); a1 = wredf(a1); a2 = wredf(a2);
  int lane = tid & 63, wv = tid >> 6;
  if (!lane) { s12[wv] = a0; s12[4 + wv] = a1; s12[8 + wv] = a2; }
  __syncthreads();
  if (!tid) {
    (ws + OFF_U)[u * 3 + 0] = s12[0] + s12[1] + s12[2] + s12[3];
    (ws + OFF_U)[u * 3 + 1] = s12[4] + s12[5] + s12[6] + s12[7];
    (ws + OFF_U)[u * 3 + 2] = s12[8] + s12[9] + s12[10] + s12[11];
  }
}

// ===== w6: out1 + mix =====
__global__ void w6(const float* __restrict__ conv1_w, const float* __restrict__ mix_w,
                   float* __restrict__ ws) {
  __shared__ float sl[4];
  int u = blockIdx.x;
  int tid = threadIdx.x;
  const float4* w4p = (const float4*)(conv1_w + (size_t)u * CW3);
  const float4* u4 = (const float4*)(ws + OFF_U);
  float acc = 0.f;
#pragma unroll
  for (int m = tid; m < CW3 / 4; m += 256) {
    float4 wv = w4p[m], uv = u4[m];
    acc += wv.x * uv.x + wv.y * uv.y + wv.z * uv.z + wv.w * uv.w;
  }
  acc = wredf(acc);
  int lane = tid & 63, wv = tid >> 6;
  if (!lane) sl[wv] = acc;
  __syncthreads();
  if (!tid) {
    float mfv = sigm(mix_w[0]);
    float o1 = sigm(sl[0] + sl[1] + sl[2] + sl[3]);
    float o2 = sigm((ws + OFF_O2)[u]);
    (ws + OFF_MIX)[u] = o1 * mfv + o2 * (1.f - mfv);
  }
}

// ===== w7: per-row mid-tap gate + final elementwise (overwrites d_out) =====
__global__ void w7(const float* __restrict__ input, const float* __restrict__ insum,
                   const float* __restrict__ conv1_w, float* __restrict__ out,
                   const float* __restrict__ ws) {
  __shared__ float sl[4];
  __shared__ float shov;
  int u = blockIdx.x;
  int tid = threadIdx.x;
  const float4* w4p = (const float4*)(conv1_w + (size_t)u * CW3);
  const float4* m4 = (const float4*)(ws + OFF_MIX);
  float acc = 0.f;
#pragma unroll
  for (int p = tid; p < 512; p += 256) {
    float4 f0 = w4p[3 * p], f1 = w4p[3 * p + 1], f2 = w4p[3 * p + 2];
    float4 m = m4[p];
    acc += f0.y * m.x + f1.x * m.y + f1.w * m.z + f2.z * m.w;
  }
  acc = wredf(acc);
  int lane = tid & 63, wv = tid >> 6;
  if (!lane) sl[wv] = acc;
  __syncthreads();
  if (!tid) shov = sigm(sl[0] + sl[1] + sl[2] + sl[3]);
  __syncthreads();
  float ovc = shov;
  const float* scal = ws + OFF_SCAL;
  float mA = scal[0], cA = scal[1], mB = scal[2], cB = scal[3];
  size_t base = (size_t)u * L;
  const float4* pa = (const float4*)(input + base);
  const float4* pb = (const float4*)(insum + base);
  float4* po = (float4*)(out + base);
#pragma unroll
  for (int i = tid; i < L / 4; i += 256) {
    float4 a = pa[i], b = pb[i], r;
    r.x = (simam1(a.x, mA, cA) * 0.6f + simam1(b.x, mB, cB) * 0.4f) * ovc;
    r.y = (simam1(a.y, mA, cA) * 0.6f + simam1(b.y, mB, cB) * 0.4f) * ovc;
    r.z = (simam1(a.z, mA, cA) * 0.6f + simam1(b.z, mB, cB) * 0.4f) * ovc;
    r.w = (simam1(a.w, mA, cA) * 0.6f + simam1(b.w, mB, cB) * 0.4f) * ovc;
    po[i] = r;
  }
}

extern "C" void kernel_launch(void* const* d_in, const int* in_sizes, int n_in,
                              void* d_out, int out_size, void* d_ws, size_t ws_size,
                              hipStream_t stream) {
  const float* input   = (const float*)d_in[0];
  const float* insum   = (const float*)d_in[1];
  const float* conv1_w = (const float*)d_in[2];
  const float* fc_w    = (const float*)d_in[3];
  const float* fc_b    = (const float*)d_in[4];
  const float* mix_w   = (const float*)d_in[5];
  float* out = (float*)d_out;
  float* ws  = (float*)d_ws;

  // zero the atomic-accumulated region: CW, G, H, V, O2 (18432 floats)
  hipMemsetAsync((char*)d_ws + OFF_CW * 4, 0, 18432 * 4, stream);

  dim3 b(256);
  w1<<<4352, b, 0, stream>>>(input, insum, fc_w, ws, out);
  w2<<<2049, b, 0, stream>>>(fc_w, fc_b, ws);
  w3<<<768, b, 0, stream>>>(conv1_w, ws);
  w4<<<1024, b, 0, stream>>>(out, ws);
  w5<<<2048, b, 0, stream>>>(out, ws);
  w6<<<2048, b, 0, stream>>>(conv1_w, mix_w, ws);
  w7<<<2048, b, 0, stream>>>(input, insum, conv1_w, out, ws);
}